// Round 1
// baseline (1690.773 us; speedup 1.0000x reference)
//
#include <hip/hip_runtime.h>

#define USER_NUM 100000
#define ITEM_NUM 50000
#define NTOT     (USER_NUM + ITEM_NUM)   // 150000
#define EMB      64
#define ELEMS    (NTOT * EMB)            // 9,600,000

// ---------------- kernels ----------------

// x0 = concat(user_emb, item_emb); acc = x0
__global__ void lgcn_init(const float* __restrict__ ue,
                          const float* __restrict__ ie,
                          float* __restrict__ x0,
                          float* __restrict__ acc) {
    int idx = blockIdx.x * blockDim.x + threadIdx.x;
    if (idx >= ELEMS) return;
    int row = idx >> 6;  // EMB = 64
    float v = (row < USER_NUM) ? ue[idx] : ie[idx - USER_NUM * EMB];
    x0[idx]  = v;
    acc[idx] = v;
}

// out[rows[i]][d] += vals[i] * x[cols[i]][d]  (atomic scatter)
// 64 consecutive threads handle one nonzero (one lane per dim).
__global__ void lgcn_spmm(const int* __restrict__ rows,
                          const int* __restrict__ cols,
                          const float* __restrict__ vals,
                          const float* __restrict__ x,
                          float* __restrict__ out,
                          int nnz) {
    long long t = (long long)blockIdx.x * blockDim.x + threadIdx.x;
    int i = (int)(t >> 6);
    int d = (int)(t & 63);
    if (i >= nnz) return;
    int   r = rows[i];
    int   c = cols[i];
    float v = vals[i];
    atomicAdd(&out[(long long)r * EMB + d], v * x[(long long)c * EMB + d]);
}

// e = (1+coef)*e - coef*m  (in place);  acc += e_new
__global__ void lgcn_combine(float* __restrict__ e,
                             const float* __restrict__ m,
                             float* __restrict__ acc,
                             float coef) {
    int idx = blockIdx.x * blockDim.x + threadIdx.x;
    if (idx >= ELEMS) return;
    float xn = (1.0f + coef) * e[idx] - coef * m[idx];
    e[idx] = xn;
    acc[idx] += xn;
}

// acc += e   (hop 3, coef == 0 so e3 == e)
__global__ void lgcn_addacc(const float* __restrict__ e,
                            float* __restrict__ acc) {
    int idx = blockIdx.x * blockDim.x + threadIdx.x;
    if (idx >= ELEMS) return;
    acc[idx] += e[idx];
}

// acc *= 0.25
__global__ void lgcn_scale(float* __restrict__ acc) {
    int idx = blockIdx.x * blockDim.x + threadIdx.x;
    if (idx >= ELEMS) return;
    acc[idx] *= 0.25f;
}

// ---------------- launch ----------------

extern "C" void kernel_launch(void* const* d_in, const int* in_sizes, int n_in,
                              void* d_out, int out_size, void* d_ws, size_t ws_size,
                              hipStream_t stream) {
    const float* ue = (const float*)d_in[0];
    const float* ie = (const float*)d_in[1];
    const int*   adj_r = (const int*)d_in[2];
    const int*   adj_c = (const int*)d_in[3];
    const float* adj_v = (const float*)d_in[4];
    const int*   aj_r  = (const int*)d_in[5];
    const int*   aj_c  = (const int*)d_in[6];
    const float* aj_v  = (const float*)d_in[7];
    const int*   ai_r  = (const int*)d_in[8];
    const int*   ai_c  = (const int*)d_in[9];
    const float* ai_v  = (const float*)d_in[10];
    const int nnz = in_sizes[2];

    float* acc  = (float*)d_out;                // [N,64] layer-sum accumulator
    float* buf0 = (float*)d_ws;
    float* buf1 = buf0 + ELEMS;
    float* buf2 = buf1 + ELEMS;
    const size_t BUFB = (size_t)ELEMS * sizeof(float);

    const int BLK = 256;
    const int gridE = (ELEMS + BLK - 1) / BLK;
    const long long spmmThreads = (long long)nnz * 64;
    const int gridS = (int)((spmmThreads + BLK - 1) / BLK);

    #define SPMM(R, C, V, X, OUT)                                              \
        do {                                                                   \
            hipMemsetAsync((OUT), 0, BUFB, stream);                            \
            lgcn_spmm<<<gridS, BLK, 0, stream>>>((R), (C), (V), (X), (OUT), nnz); \
        } while (0)

    // x0 = ego, acc = ego
    lgcn_init<<<gridE, BLK, 0, stream>>>(ue, ie, buf0, acc);

    // ---- hop 1 (coef 0.1): x=buf0 ----
    SPMM(adj_r, adj_c, adj_v, buf0, buf1);   // e1 = adj @ x0
    SPMM(aj_r,  aj_c,  aj_v,  buf1, buf0);   // t  = aj @ e1   (x0 dead)
    SPMM(ai_r,  ai_c,  ai_v,  buf0, buf2);   // m  = ai @ t
    lgcn_combine<<<gridE, BLK, 0, stream>>>(buf1, buf2, acc, 0.1f);  // x1 in buf1

    // ---- hop 2 (coef 0.1): x=buf1 ----
    SPMM(adj_r, adj_c, adj_v, buf1, buf0);   // e2 = adj @ x1
    SPMM(aj_r,  aj_c,  aj_v,  buf0, buf1);   // t  = aj @ e2   (x1 dead)
    SPMM(ai_r,  ai_c,  ai_v,  buf1, buf2);   // m  = ai @ t
    lgcn_combine<<<gridE, BLK, 0, stream>>>(buf0, buf2, acc, 0.1f);  // x2 in buf0

    // ---- hop 3 (coef 0.0): e3 = adj @ x2 exactly; aj/ai SpMMs are dead ----
    SPMM(adj_r, adj_c, adj_v, buf0, buf1);   // e3
    lgcn_addacc<<<gridE, BLK, 0, stream>>>(buf1, acc);

    // mean over {ego, e1, e2, e3}
    lgcn_scale<<<gridE, BLK, 0, stream>>>(acc);

    #undef SPMM
}

// Round 2
// 905.249 us; speedup vs baseline: 1.8677x; 1.8677x over previous
//
#include <hip/hip_runtime.h>

#define USER_NUM 100000
#define ITEM_NUM 50000
#define NROWS    (USER_NUM + ITEM_NUM)   // 150000
#define RP       (NROWS + 1)
#define EMB      64
#define ELEMS    (NROWS * EMB)           // 9,600,000
#define SCAN_BLK 256

// ============ shared helpers ============

__global__ void lgcn_init(const float* __restrict__ ue,
                          const float* __restrict__ ie,
                          float* __restrict__ x0,
                          float* __restrict__ acc) {
    int idx = blockIdx.x * blockDim.x + threadIdx.x;
    if (idx >= ELEMS) return;
    int row = idx >> 6;
    float v = (row < USER_NUM) ? ue[idx] : ie[idx - USER_NUM * EMB];
    x0[idx]  = v;
    acc[idx] = v;
}

// ============ CSR build ============

__global__ void csr_hist(const int* __restrict__ rows, int* __restrict__ counts, int nnz) {
    int i = blockIdx.x * blockDim.x + threadIdx.x;
    if (i >= nnz) return;
    atomicAdd(&counts[rows[i]], 1);
}

// per-block inclusive scan; rowptr[i+1] = partial, bsum[b] = block total
__global__ void csr_scan1(const int* __restrict__ counts, int* __restrict__ rowptr,
                          int* __restrict__ bsum, int n) {
    __shared__ int sh[SCAN_BLK];
    int i = blockIdx.x * SCAN_BLK + threadIdx.x;
    sh[threadIdx.x] = (i < n) ? counts[i] : 0;
    __syncthreads();
    for (int ofs = 1; ofs < SCAN_BLK; ofs <<= 1) {
        int t = (threadIdx.x >= ofs) ? sh[threadIdx.x - ofs] : 0;
        __syncthreads();
        sh[threadIdx.x] += t;
        __syncthreads();
    }
    if (i < n) rowptr[i + 1] = sh[threadIdx.x];
    if (threadIdx.x == SCAN_BLK - 1) bsum[blockIdx.x] = sh[threadIdx.x];
}

// single-block exclusive scan of block sums (staged through LDS)
__global__ void csr_scan2(int* __restrict__ bsum, int nb,
                          int* __restrict__ rowptr, int* __restrict__ fill) {
    __shared__ int sh[1024];
    int tid = threadIdx.x;
    for (int i = tid; i < nb; i += blockDim.x) sh[i] = bsum[i];
    __syncthreads();
    if (tid == 0) {
        int run = 0;
        for (int b = 0; b < nb; ++b) { int t = sh[b]; sh[b] = run; run += t; }
        rowptr[0] = 0;
        fill[0]   = 0;
    }
    __syncthreads();
    for (int i = tid; i < nb; i += blockDim.x) bsum[i] = sh[i];
}

__global__ void csr_scan3(int* __restrict__ rowptr, int* __restrict__ fill,
                          const int* __restrict__ bsum, int n) {
    int i = blockIdx.x * SCAN_BLK + threadIdx.x;
    if (i >= n) return;
    int v = rowptr[i + 1] + bsum[blockIdx.x];
    rowptr[i + 1] = v;
    if (i + 1 < n) fill[i + 1] = v;
}

__global__ void csr_scatter(const int* __restrict__ rows, const int* __restrict__ cols,
                            const float* __restrict__ vals,
                            int* __restrict__ fill,
                            int* __restrict__ ccols, float* __restrict__ cvals, int nnz) {
    int i = blockIdx.x * blockDim.x + threadIdx.x;
    if (i >= nnz) return;
    int p = atomicAdd(&fill[rows[i]], 1);
    ccols[p] = cols[i];
    cvals[p] = vals[i];
}

// ============ CSR SpMM (one 64-lane wave per row, lane = dim) ============

__device__ __forceinline__ float row_dot(const int* __restrict__ rp,
                                         const int* __restrict__ cc,
                                         const float* __restrict__ cv,
                                         const float* __restrict__ x,
                                         int row, int d) {
    int s = rp[row], e = rp[row + 1];
    float a0 = 0.f, a1 = 0.f;
    int i = s;
    for (; i + 1 < e; i += 2) {
        int   c0 = cc[i],   c1 = cc[i + 1];
        float v0 = cv[i],   v1 = cv[i + 1];
        a0 = fmaf(v0, x[(c0 << 6) + d], a0);
        a1 = fmaf(v1, x[(c1 << 6) + d], a1);
    }
    if (i < e) a0 = fmaf(cv[i], x[(cc[i] << 6) + d], a0);
    return a0 + a1;
}

__global__ void spmm_plain(const int* __restrict__ rp, const int* __restrict__ cc,
                           const float* __restrict__ cv, const float* __restrict__ x,
                           float* __restrict__ out) {
    int idx = blockIdx.x * blockDim.x + threadIdx.x;
    if (idx >= ELEMS) return;
    out[idx] = row_dot(rp, cc, cv, x, idx >> 6, idx & 63);
}

// xnext = (1+coef)*e - coef*(Ai @ t);  out=xnext; acc+=xnext
__global__ void spmm_combine(const int* __restrict__ rp, const int* __restrict__ cc,
                             const float* __restrict__ cv, const float* __restrict__ t,
                             const float* __restrict__ e,
                             float* __restrict__ out, float* __restrict__ acc, float coef) {
    int idx = blockIdx.x * blockDim.x + threadIdx.x;
    if (idx >= ELEMS) return;
    float m  = row_dot(rp, cc, cv, t, idx >> 6, idx & 63);
    float xn = (1.0f + coef) * e[idx] - coef * m;
    out[idx] = xn;
    acc[idx] += xn;
}

// acc = (acc + adj @ x) * 0.25   (hop 3, coef==0)
__global__ void spmm_final(const int* __restrict__ rp, const int* __restrict__ cc,
                           const float* __restrict__ cv, const float* __restrict__ x,
                           float* __restrict__ acc) {
    int idx = blockIdx.x * blockDim.x + threadIdx.x;
    if (idx >= ELEMS) return;
    float e3 = row_dot(rp, cc, cv, x, idx >> 6, idx & 63);
    acc[idx] = (acc[idx] + e3) * 0.25f;
}

// ============ fallback (round-1 atomic path) ============

__global__ void lgcn_spmm_atomic(const int* __restrict__ rows, const int* __restrict__ cols,
                                 const float* __restrict__ vals, const float* __restrict__ x,
                                 float* __restrict__ out, int nnz) {
    long long t = (long long)blockIdx.x * blockDim.x + threadIdx.x;
    int i = (int)(t >> 6);
    int d = (int)(t & 63);
    if (i >= nnz) return;
    atomicAdd(&out[(long long)rows[i] * EMB + d], vals[i] * x[(long long)cols[i] * EMB + d]);
}
__global__ void lgcn_combine_eltwise(float* __restrict__ e, const float* __restrict__ m,
                                     float* __restrict__ acc, float coef) {
    int idx = blockIdx.x * blockDim.x + threadIdx.x;
    if (idx >= ELEMS) return;
    float xn = (1.0f + coef) * e[idx] - coef * m[idx];
    e[idx] = xn;
    acc[idx] += xn;
}
__global__ void lgcn_final_eltwise(const float* __restrict__ e, float* __restrict__ acc) {
    int idx = blockIdx.x * blockDim.x + threadIdx.x;
    if (idx >= ELEMS) return;
    acc[idx] = (acc[idx] + e[idx]) * 0.25f;
}

// ============ launch ============

extern "C" void kernel_launch(void* const* d_in, const int* in_sizes, int n_in,
                              void* d_out, int out_size, void* d_ws, size_t ws_size,
                              hipStream_t stream) {
    const float* ue = (const float*)d_in[0];
    const float* ie = (const float*)d_in[1];
    const int*   R[3] = { (const int*)d_in[2], (const int*)d_in[5], (const int*)d_in[8] };
    const int*   C[3] = { (const int*)d_in[3], (const int*)d_in[6], (const int*)d_in[9] };
    const float* V[3] = { (const float*)d_in[4], (const float*)d_in[7], (const float*)d_in[10] };
    const int    NZ[3] = { in_sizes[2], in_sizes[5], in_sizes[8] };

    float* acc = (float*)d_out;

    const int BLK   = 256;
    const int gridE = (ELEMS + BLK - 1) / BLK;     // 37500
    const int nbScan = (NROWS + SCAN_BLK - 1) / SCAN_BLK;  // 586

    // ---- workspace carve ----
    float* bufA = (float*)d_ws;
    float* bufB = bufA + ELEMS;
    float* bufC = bufB + ELEMS;
    int*   cur  = (int*)(bufC + ELEMS);

    int* rp[3]; int* cc[3]; float* cv[3];
    for (int m = 0; m < 3; ++m) {
        rp[m] = cur;               cur += ((RP + 3) & ~3);
        cc[m] = cur;               cur += ((NZ[m] + 3) & ~3);
        cv[m] = (float*)cur;       cur += ((NZ[m] + 3) & ~3);
    }
    int* counts = cur;  cur += ((NROWS + 3) & ~3);
    int* fill   = cur;  cur += ((NROWS + 3) & ~3);
    int* bsum   = cur;  cur += 1024;
    size_t need = (size_t)((char*)cur - (char*)d_ws);

    if (ws_size < need) {
        // -------- fallback: round-1 atomic COO path (needs only 3 dense bufs) --------
        const size_t BUFB = (size_t)ELEMS * sizeof(float);
        #define ASPMM(MI, X, OUT)                                                      \
            do {                                                                       \
                hipMemsetAsync((OUT), 0, BUFB, stream);                                \
                int g = (int)(((long long)NZ[MI] * 64 + BLK - 1) / BLK);               \
                lgcn_spmm_atomic<<<g, BLK, 0, stream>>>(R[MI], C[MI], V[MI], (X), (OUT), NZ[MI]); \
            } while (0)
        lgcn_init<<<gridE, BLK, 0, stream>>>(ue, ie, bufA, acc);
        ASPMM(0, bufA, bufB); ASPMM(1, bufB, bufA); ASPMM(2, bufA, bufC);
        lgcn_combine_eltwise<<<gridE, BLK, 0, stream>>>(bufB, bufC, acc, 0.1f);
        ASPMM(0, bufB, bufA); ASPMM(1, bufA, bufB); ASPMM(2, bufB, bufC);
        lgcn_combine_eltwise<<<gridE, BLK, 0, stream>>>(bufA, bufC, acc, 0.1f);
        ASPMM(0, bufA, bufB);
        lgcn_final_eltwise<<<gridE, BLK, 0, stream>>>(bufB, acc);
        #undef ASPMM
        return;
    }

    // ---- build CSR for the 3 matrices ----
    for (int m = 0; m < 3; ++m) {
        int gH = (NZ[m] + BLK - 1) / BLK;
        hipMemsetAsync(counts, 0, NROWS * sizeof(int), stream);
        csr_hist   <<<gH, BLK, 0, stream>>>(R[m], counts, NZ[m]);
        csr_scan1  <<<nbScan, SCAN_BLK, 0, stream>>>(counts, rp[m], bsum, NROWS);
        csr_scan2  <<<1, 1024, 0, stream>>>(bsum, nbScan, rp[m], fill);
        csr_scan3  <<<nbScan, SCAN_BLK, 0, stream>>>(rp[m], fill, bsum, NROWS);
        csr_scatter<<<gH, BLK, 0, stream>>>(R[m], C[m], V[m], fill, cc[m], cv[m], NZ[m]);
    }

    // ---- x0 = ego; acc = ego ----
    lgcn_init<<<gridE, BLK, 0, stream>>>(ue, ie, bufA, acc);

    // ---- hop 1 (coef 0.1), x = bufA ----
    spmm_plain  <<<gridE, BLK, 0, stream>>>(rp[0], cc[0], cv[0], bufA, bufB);          // e1
    spmm_plain  <<<gridE, BLK, 0, stream>>>(rp[1], cc[1], cv[1], bufB, bufA);          // t
    spmm_combine<<<gridE, BLK, 0, stream>>>(rp[2], cc[2], cv[2], bufA, bufB, bufC, acc, 0.1f); // x1 -> bufC

    // ---- hop 2 (coef 0.1), x = bufC ----
    spmm_plain  <<<gridE, BLK, 0, stream>>>(rp[0], cc[0], cv[0], bufC, bufA);          // e2
    spmm_plain  <<<gridE, BLK, 0, stream>>>(rp[1], cc[1], cv[1], bufA, bufB);          // t
    spmm_combine<<<gridE, BLK, 0, stream>>>(rp[2], cc[2], cv[2], bufB, bufA, bufC, acc, 0.1f); // x2 -> bufC

    // ---- hop 3 (coef 0.0): acc = (acc + adj@x2) * 0.25 ----
    spmm_final  <<<gridE, BLK, 0, stream>>>(rp[0], cc[0], cv[0], bufC, acc);
}

// Round 3
// 717.052 us; speedup vs baseline: 2.3579x; 1.2625x over previous
//
#include <hip/hip_runtime.h>
#include <hip/hip_fp16.h>

#define USER_NUM 100000
#define ITEM_NUM 50000
#define NROWS    (USER_NUM + ITEM_NUM)   // 150000
#define EMB      64
#define ELEMS    (NROWS * EMB)           // 9,600,000  (divisible by 256)
#define NMAT     3
#define NCNT     (NMAT * NROWS)          // 450000
#define SCAN_BLK 256

// ================= CSR build (fused across the 3 matrices) =================

__global__ void csr_hist(const int* __restrict__ rows, int* __restrict__ counts, int nnz) {
    int i = blockIdx.x * blockDim.x + threadIdx.x;
    if (i >= nnz) return;
    atomicAdd(&counts[rows[i]], 1);
}

// per-block inclusive scan of counts; rowptr[i+1] = partial, bsum[b] = block total
__global__ void csr_scan1(const int* __restrict__ counts, int* __restrict__ rowptr,
                          int* __restrict__ bsum, int n) {
    __shared__ int sh[SCAN_BLK];
    int i = blockIdx.x * SCAN_BLK + threadIdx.x;
    sh[threadIdx.x] = (i < n) ? counts[i] : 0;
    __syncthreads();
    for (int ofs = 1; ofs < SCAN_BLK; ofs <<= 1) {
        int t = (threadIdx.x >= ofs) ? sh[threadIdx.x - ofs] : 0;
        __syncthreads();
        sh[threadIdx.x] += t;
        __syncthreads();
    }
    if (i < n) rowptr[i + 1] = sh[threadIdx.x];
    if (threadIdx.x == SCAN_BLK - 1) bsum[blockIdx.x] = sh[threadIdx.x];
}

// parallel exclusive scan of nb block sums (single block, chunked)
__global__ void csr_scan2(int* __restrict__ bsum, int nb,
                          int* __restrict__ rowptr, int* __restrict__ fill) {
    __shared__ int tsum[256];
    int tid = threadIdx.x;
    int C = (nb + 255) >> 8;
    int start = tid * C;
    int end = start + C; if (end > nb) end = nb;
    int local = 0;
    for (int i = start; i < end; ++i) local += bsum[i];
    tsum[tid] = local;
    __syncthreads();
    for (int ofs = 1; ofs < 256; ofs <<= 1) {
        int t = (tid >= ofs) ? tsum[tid - ofs] : 0;
        __syncthreads();
        tsum[tid] += t;
        __syncthreads();
    }
    int run = (tid > 0) ? tsum[tid - 1] : 0;
    for (int i = start; i < end; ++i) { int v = bsum[i]; bsum[i] = run; run += v; }
    if (tid == 0) { rowptr[0] = 0; fill[0] = 0; }
}

__global__ void csr_scan3(int* __restrict__ rowptr, int* __restrict__ fill,
                          const int* __restrict__ bsum, int n) {
    int i = blockIdx.x * SCAN_BLK + threadIdx.x;
    if (i >= n) return;
    int v = rowptr[i + 1] + bsum[blockIdx.x];
    rowptr[i + 1] = v;
    if (i + 1 < n) fill[i + 1] = v;
}

// scatter into packed {col, val_bits} entries at globally-scanned offsets
__global__ void csr_scatter(const int* __restrict__ rows, const int* __restrict__ cols,
                            const float* __restrict__ vals,
                            int* __restrict__ fill,
                            int2* __restrict__ pk, int nnz) {
    int i = blockIdx.x * blockDim.x + threadIdx.x;
    if (i >= nnz) return;
    int p = atomicAdd(&fill[rows[i]], 1);
    pk[p] = make_int2(cols[i], __float_as_int(vals[i]));
}

// ================= init: x0 = concat(ue, ie) as fp16 =================
// vectorized: one thread = 4 elements

__global__ void lgcn_init4(const float* __restrict__ ue,
                           const float* __restrict__ ie,
                           __half* __restrict__ x0) {
    int i4 = blockIdx.x * blockDim.x + threadIdx.x;   // ELEMS/4 threads, exact
    int base = i4 << 2;
    int row = base >> 6;
    float4 v = (row < USER_NUM)
        ? ((const float4*)ue)[i4]
        : ((const float4*)(ie))[i4 - (USER_NUM * EMB >> 2)];
    __half2 h01 = __floats2half2_rn(v.x, v.y);
    __half2 h23 = __floats2half2_rn(v.z, v.w);
    uint2 packed;
    packed.x = *(const unsigned int*)&h01;
    packed.y = *(const unsigned int*)&h23;
    ((uint2*)x0)[i4] = packed;
}

// ================= CSR SpMM: one 64-lane wave per row, lane = dim =================

__device__ __forceinline__ float row_dot(const int* __restrict__ rp,
                                         const int2* __restrict__ pk,
                                         const __half* __restrict__ x,
                                         int row, int d) {
    int s = rp[row], e = rp[row + 1];       // wave-uniform -> scalar loads
    float a0 = 0.f, a1 = 0.f;
    int i = s;
    for (; i + 1 < e; i += 2) {
        int2 p0 = pk[i], p1 = pk[i + 1];    // wave-uniform
        a0 = fmaf(__int_as_float(p0.y), __half2float(x[(p0.x << 6) + d]), a0);
        a1 = fmaf(__int_as_float(p1.y), __half2float(x[(p1.x << 6) + d]), a1);
    }
    if (i < e) {
        int2 p = pk[i];
        a0 = fmaf(__int_as_float(p.y), __half2float(x[(p.x << 6) + d]), a0);
    }
    return a0 + a1;
}

__global__ void spmm_plain(const int* __restrict__ rp, const int2* __restrict__ pk,
                           const __half* __restrict__ x, __half* __restrict__ out) {
    int idx = blockIdx.x * blockDim.x + threadIdx.x;   // ELEMS exact
    int row = __builtin_amdgcn_readfirstlane(idx >> 6);
    int d = threadIdx.x & 63;
    out[idx] = __float2half(row_dot(rp, pk, x, row, d));
}

// xnext = (1+coef)*e - coef*(Ai @ t)
__global__ void spmm_combine(const int* __restrict__ rp, const int2* __restrict__ pk,
                             const __half* __restrict__ t, const __half* __restrict__ e,
                             __half* __restrict__ xout, float coef) {
    int idx = blockIdx.x * blockDim.x + threadIdx.x;
    int row = __builtin_amdgcn_readfirstlane(idx >> 6);
    int d = threadIdx.x & 63;
    float m = row_dot(rp, pk, t, row, d);
    float xn = (1.0f + coef) * __half2float(e[idx]) - coef * m;
    xout[idx] = __float2half(xn);
}

// out = (x0 + x1 + x2 + adj@x2) * 0.25   (hop 3, coef==0, fused layer mean)
__global__ void spmm_final4(const int* __restrict__ rp, const int2* __restrict__ pk,
                            const __half* __restrict__ x2, const __half* __restrict__ x0,
                            const __half* __restrict__ x1, float* __restrict__ acc) {
    int idx = blockIdx.x * blockDim.x + threadIdx.x;
    int row = __builtin_amdgcn_readfirstlane(idx >> 6);
    int d = threadIdx.x & 63;
    float e3 = row_dot(rp, pk, x2, row, d);
    float s = __half2float(x0[idx]) + __half2float(x1[idx]) + __half2float(x2[idx]) + e3;
    acc[idx] = 0.25f * s;
}

// ================= launch =================

extern "C" void kernel_launch(void* const* d_in, const int* in_sizes, int n_in,
                              void* d_out, int out_size, void* d_ws, size_t ws_size,
                              hipStream_t stream) {
    const float* ue = (const float*)d_in[0];
    const float* ie = (const float*)d_in[1];
    const int*   R[3] = { (const int*)d_in[2], (const int*)d_in[5], (const int*)d_in[8] };
    const int*   C[3] = { (const int*)d_in[3], (const int*)d_in[6], (const int*)d_in[9] };
    const float* V[3] = { (const float*)d_in[4], (const float*)d_in[7], (const float*)d_in[10] };
    const int    NZ[3] = { in_sizes[2], in_sizes[5], in_sizes[8] };
    const int    NZT = NZ[0] + NZ[1] + NZ[2];

    float* acc = (float*)d_out;

    // ---- workspace carve (8B-aligned pieces first) ----
    char* cur = (char*)d_ws;
    int2* pk = (int2*)cur;            cur += (size_t)NZT * sizeof(int2);
    int* rpg    = (int*)cur;          cur += ((size_t)(NCNT + 1 + 1) & ~1ull) * sizeof(int);
    int* counts = (int*)cur;          cur += (size_t)NCNT * sizeof(int);
    int* fill   = (int*)cur;          cur += (size_t)NCNT * sizeof(int);
    int* bsum   = (int*)cur;          cur += 2048 * sizeof(int);
    __half* x0  = (__half*)cur;       cur += (size_t)ELEMS * sizeof(__half);
    __half* x1  = (__half*)cur;       cur += (size_t)ELEMS * sizeof(__half);
    __half* x2  = (__half*)cur;       cur += (size_t)ELEMS * sizeof(__half);
    __half* tE  = (__half*)cur;       cur += (size_t)ELEMS * sizeof(__half);
    __half* tT  = (__half*)cur;       cur += (size_t)ELEMS * sizeof(__half);
    (void)ws_size;

    const int BLK = 256;
    const int gridE  = ELEMS / BLK;                      // 37500, exact
    const int gridI  = (ELEMS / 4) / BLK;                // 9375, exact
    const int nbScan = (NCNT + SCAN_BLK - 1) / SCAN_BLK; // 1758

    // ---- fused CSR build over all 3 matrices ----
    hipMemsetAsync(counts, 0, (size_t)NCNT * sizeof(int), stream);
    for (int m = 0; m < 3; ++m) {
        int g = (NZ[m] + BLK - 1) / BLK;
        csr_hist<<<g, BLK, 0, stream>>>(R[m], counts + m * NROWS, NZ[m]);
    }
    csr_scan1<<<nbScan, SCAN_BLK, 0, stream>>>(counts, rpg, bsum, NCNT);
    csr_scan2<<<1, 256, 0, stream>>>(bsum, nbScan, rpg, fill);
    csr_scan3<<<nbScan, SCAN_BLK, 0, stream>>>(rpg, fill, bsum, NCNT);
    for (int m = 0; m < 3; ++m) {
        int g = (NZ[m] + BLK - 1) / BLK;
        csr_scatter<<<g, BLK, 0, stream>>>(R[m], C[m], V[m], fill + m * NROWS, pk, NZ[m]);
    }

    const int* rpAdj = rpg;                 // matrix 0
    const int* rpAj  = rpg + 1 * NROWS;     // matrix 1
    const int* rpAi  = rpg + 2 * NROWS;     // matrix 2

    // ---- x0 = ego (fp16) ----
    lgcn_init4<<<gridI, BLK, 0, stream>>>(ue, ie, x0);

    // ---- hop 1 (coef 0.1) ----
    spmm_plain  <<<gridE, BLK, 0, stream>>>(rpAdj, pk, x0, tE);             // e1
    spmm_plain  <<<gridE, BLK, 0, stream>>>(rpAj,  pk, tE, tT);             // t1
    spmm_combine<<<gridE, BLK, 0, stream>>>(rpAi,  pk, tT, tE, x1, 0.1f);   // x1

    // ---- hop 2 (coef 0.1) ----
    spmm_plain  <<<gridE, BLK, 0, stream>>>(rpAdj, pk, x1, tE);             // e2
    spmm_plain  <<<gridE, BLK, 0, stream>>>(rpAj,  pk, tE, tT);             // t2
    spmm_combine<<<gridE, BLK, 0, stream>>>(rpAi,  pk, tT, tE, x2, 0.1f);   // x2

    // ---- hop 3 (coef 0.0) + fused layer mean ----
    spmm_final4 <<<gridE, BLK, 0, stream>>>(rpAdj, pk, x2, x0, x1, acc);
}

// Round 4
// 464.566 us; speedup vs baseline: 3.6395x; 1.5435x over previous
//
#include <hip/hip_runtime.h>
#include <hip/hip_fp16.h>

#define USER_NUM 100000
#define ITEM_NUM 50000
#define NROWS    150000
#define EMB      64
#define ELEMS    (NROWS * EMB)            // 9,600,000
#define BROWS    1024                     // rows per sort bucket
#define NBM      147                      // ceil(NROWS / BROWS)
#define NBT      (3 * NBM)                // 441 buckets across 3 matrices
#define RPSTRIDE (NROWS + 1)
#define P1_CHUNK 4096

// ================= bucket histogram (gridDim.y = matrix) =================

__global__ void bucket_hist(const int* __restrict__ r0, const int* __restrict__ r1,
                            const int* __restrict__ r2, int n0, int n1, int n2,
                            int* __restrict__ bcnt) {
    const int m = blockIdx.y;
    const int* rows = (m == 0) ? r0 : (m == 1) ? r1 : r2;
    const int  nnz  = (m == 0) ? n0 : (m == 1) ? n1 : n2;
    __shared__ int cnt[NBM];
    for (int i = threadIdx.x; i < NBM; i += blockDim.x) cnt[i] = 0;
    __syncthreads();
    for (int i = blockIdx.x * blockDim.x + threadIdx.x; i < nnz; i += gridDim.x * blockDim.x)
        atomicAdd(&cnt[rows[i] >> 10], 1);
    __syncthreads();
    int* g = bcnt + m * NBM;
    for (int i = threadIdx.x; i < NBM; i += blockDim.x) {
        int c = cnt[i];
        if (c) atomicAdd(&g[i], c);
    }
}

// exclusive scan of the 441 bucket sizes (single block); bbase[NBT] = total
__global__ void bucket_scan(const int* __restrict__ bcnt, int* __restrict__ bbase,
                            int* __restrict__ bfill) {
    __shared__ int sh[512];
    int t = threadIdx.x;
    sh[t] = (t < NBT) ? bcnt[t] : 0;
    __syncthreads();
    for (int o = 1; o < 512; o <<= 1) {
        int v = (t >= o) ? sh[t - o] : 0;
        __syncthreads();
        sh[t] += v;
        __syncthreads();
    }
    int ex = t ? sh[t - 1] : 0;
    if (t <= NBT) bbase[t] = ex;
    if (t < NBT)  bfill[t] = ex;
}

// bin entries into bucket regions with block-aggregated reservations.
// key packs (row & 1023) << 18 | col   (col < 150000 < 2^18)
__global__ void bucket_bin(const int* __restrict__ r0, const int* __restrict__ c0, const float* __restrict__ v0,
                           const int* __restrict__ r1, const int* __restrict__ c1, const float* __restrict__ v1,
                           const int* __restrict__ r2, const int* __restrict__ c2, const float* __restrict__ v2,
                           int n0, int n1, int n2,
                           int* __restrict__ bfill, int2* __restrict__ tmp) {
    const int m = blockIdx.y;
    const int*   rows = (m == 0) ? r0 : (m == 1) ? r1 : r2;
    const int*   cols = (m == 0) ? c0 : (m == 1) ? c1 : c2;
    const float* vals = (m == 0) ? v0 : (m == 1) ? v1 : v2;
    const int    nnz  = (m == 0) ? n0 : (m == 1) ? n1 : n2;

    int start = blockIdx.x * P1_CHUNK;
    if (start >= nnz) return;
    int end = start + P1_CHUNK;
    if (end > nnz) end = nnz;

    __shared__ int lcnt[NBM];
    __shared__ int lbase[NBM];
    for (int i = threadIdx.x; i < NBM; i += blockDim.x) lcnt[i] = 0;
    __syncthreads();
    for (int i = start + threadIdx.x; i < end; i += blockDim.x)
        atomicAdd(&lcnt[rows[i] >> 10], 1);
    __syncthreads();
    int* gf = bfill + m * NBM;
    for (int i = threadIdx.x; i < NBM; i += blockDim.x) {
        int c = lcnt[i];
        lbase[i] = c ? atomicAdd(&gf[i], c) : 0;
    }
    __syncthreads();
    for (int i = threadIdx.x; i < NBM; i += blockDim.x) lcnt[i] = 0;
    __syncthreads();
    for (int i = start + threadIdx.x; i < end; i += blockDim.x) {
        int r = rows[i];
        int b = r >> 10;
        int pos = lbase[b] + atomicAdd(&lcnt[b], 1);
        tmp[pos] = make_int2(((r & 1023) << 18) | cols[i], __float_as_int(vals[i]));
    }
}

// per-bucket LDS counting sort -> final CSR segment + rowptr (one block per bucket)
__global__ void bucket_sort(const int2* __restrict__ tmp, const int* __restrict__ bbase,
                            int2* __restrict__ pk, int* __restrict__ rpg) {
    int gb = blockIdx.x;
    int m  = gb / NBM;
    int lb = gb - m * NBM;
    int base = bbase[gb];
    int next = bbase[gb + 1];
    int r0 = lb << 10;
    int cover = NROWS - r0; if (cover > BROWS) cover = BROWS;

    __shared__ int cnt[BROWS];
    __shared__ int tsum[256];
    int t = threadIdx.x;
    for (int i = t; i < BROWS; i += 256) cnt[i] = 0;
    __syncthreads();
    for (int i = base + t; i < next; i += 256) atomicAdd(&cnt[tmp[i].x >> 18], 1);
    __syncthreads();
    // 256-thread scan of 1024 counters (4 per thread)
    int c0 = cnt[4*t], c1 = cnt[4*t+1], c2 = cnt[4*t+2], c3 = cnt[4*t+3];
    int s = c0 + c1 + c2 + c3;
    tsum[t] = s;
    __syncthreads();
    for (int o = 1; o < 256; o <<= 1) {
        int v = (t >= o) ? tsum[t - o] : 0;
        __syncthreads();
        tsum[t] += v;
        __syncthreads();
    }
    int ex = t ? tsum[t - 1] : 0;
    cnt[4*t] = ex; cnt[4*t+1] = ex + c0; cnt[4*t+2] = ex + c0 + c1; cnt[4*t+3] = ex + c0 + c1 + c2;
    __syncthreads();
    int* rp = rpg + m * RPSTRIDE;
    for (int k = t; k < cover; k += 256) rp[r0 + k] = base + cnt[k];
    if (t == 0) rp[r0 + cover] = next;   // benign equal-value overlap with next bucket
    __syncthreads();
    for (int i = base + t; i < next; i += 256) {
        int2 e2 = tmp[i];
        int r = e2.x >> 18;
        int pos = base + atomicAdd(&cnt[r], 1);
        pk[pos] = make_int2(e2.x & 0x3FFFF, e2.y);
    }
}

// ================= init: x0 = concat(ue, ie) as fp16 =================

__global__ void lgcn_init4(const float* __restrict__ ue,
                           const float* __restrict__ ie,
                           __half* __restrict__ x0) {
    int i4 = blockIdx.x * blockDim.x + threadIdx.x;   // ELEMS/4 threads, exact
    int base = i4 << 2;
    int row = base >> 6;
    float4 v = (row < USER_NUM)
        ? ((const float4*)ue)[i4]
        : ((const float4*)ie)[i4 - (USER_NUM * EMB >> 2)];
    __half2 h01 = __floats2half2_rn(v.x, v.y);
    __half2 h23 = __floats2half2_rn(v.z, v.w);
    uint2 packed;
    packed.x = *(const unsigned int*)&h01;
    packed.y = *(const unsigned int*)&h23;
    ((uint2*)x0)[i4] = packed;
}

// ================= SpMM: one wave per row, 4 nonzeros in flight =================
// lane = g*16 + k ; group g handles entries s+g, s+g+4, ... ; lane covers dims [4k..4k+3]

__device__ __forceinline__ float4 row_dot4(const int* __restrict__ rp,
                                           const int2* __restrict__ pk,
                                           const __half* __restrict__ x,
                                           int row, int g, int k4) {
    int s = rp[row], e = rp[row + 1];     // wave-uniform -> scalar loads
    float4 acc = make_float4(0.f, 0.f, 0.f, 0.f);
    for (int i = s + g; i < e; i += 4) {
        int2 p = pk[i];
        float v = __int_as_float(p.y);
        uint2 u = *(const uint2*)(x + (p.x << 6) + k4);   // 8B = 4 halves
        float2 f0 = __half22float2(*(__half2*)&u.x);
        float2 f1 = __half22float2(*(__half2*)&u.y);
        acc.x = fmaf(v, f0.x, acc.x);
        acc.y = fmaf(v, f0.y, acc.y);
        acc.z = fmaf(v, f1.x, acc.z);
        acc.w = fmaf(v, f1.y, acc.w);
    }
    acc.x += __shfl_xor(acc.x, 16); acc.y += __shfl_xor(acc.y, 16);
    acc.z += __shfl_xor(acc.z, 16); acc.w += __shfl_xor(acc.w, 16);
    acc.x += __shfl_xor(acc.x, 32); acc.y += __shfl_xor(acc.y, 32);
    acc.z += __shfl_xor(acc.z, 32); acc.w += __shfl_xor(acc.w, 32);
    return acc;
}

__global__ void spmm_plain(const int* __restrict__ rp, const int2* __restrict__ pk,
                           const __half* __restrict__ x, __half* __restrict__ out) {
    int lane = threadIdx.x & 63;
    int w = (blockIdx.x << 2) + (threadIdx.x >> 6);
    int row = __builtin_amdgcn_readfirstlane(w);
    int g = lane >> 4, k4 = (lane & 15) << 2;
    float4 a = row_dot4(rp, pk, x, row, g, k4);
    if (g == 0) {
        __half2 h0 = __floats2half2_rn(a.x, a.y);
        __half2 h1 = __floats2half2_rn(a.z, a.w);
        uint2 o = make_uint2(*(unsigned*)&h0, *(unsigned*)&h1);
        *(uint2*)(out + (row << 6) + k4) = o;
    }
}

// xnext = (1+coef)*e - coef*(Ai @ t)
__global__ void spmm_combine(const int* __restrict__ rp, const int2* __restrict__ pk,
                             const __half* __restrict__ tx, const __half* __restrict__ ex,
                             __half* __restrict__ xout, float coef) {
    int lane = threadIdx.x & 63;
    int w = (blockIdx.x << 2) + (threadIdx.x >> 6);
    int row = __builtin_amdgcn_readfirstlane(w);
    int g = lane >> 4, k4 = (lane & 15) << 2;
    float4 mm = row_dot4(rp, pk, tx, row, g, k4);
    if (g == 0) {
        uint2 u = *(const uint2*)(ex + (row << 6) + k4);
        float2 e0 = __half22float2(*(__half2*)&u.x);
        float2 e1 = __half22float2(*(__half2*)&u.y);
        float cp = 1.0f + coef;
        __half2 h0 = __floats2half2_rn(cp * e0.x - coef * mm.x, cp * e0.y - coef * mm.y);
        __half2 h1 = __floats2half2_rn(cp * e1.x - coef * mm.z, cp * e1.y - coef * mm.w);
        uint2 o = make_uint2(*(unsigned*)&h0, *(unsigned*)&h1);
        *(uint2*)(xout + (row << 6) + k4) = o;
    }
}

// acc = (x0 + x1 + x2 + adj@x2) * 0.25  (hop 3, coef==0, fused layer mean, f32 out)
__global__ void spmm_final(const int* __restrict__ rp, const int2* __restrict__ pk,
                           const __half* __restrict__ x2, const __half* __restrict__ x0,
                           const __half* __restrict__ x1, float* __restrict__ acc) {
    int lane = threadIdx.x & 63;
    int w = (blockIdx.x << 2) + (threadIdx.x >> 6);
    int row = __builtin_amdgcn_readfirstlane(w);
    int g = lane >> 4, k4 = (lane & 15) << 2;
    float4 e3 = row_dot4(rp, pk, x2, row, g, k4);
    if (g == 0) {
        int off = (row << 6) + k4;
        uint2 u0 = *(const uint2*)(x0 + off);
        uint2 u1 = *(const uint2*)(x1 + off);
        uint2 u2 = *(const uint2*)(x2 + off);
        float2 a0 = __half22float2(*(__half2*)&u0.x), b0 = __half22float2(*(__half2*)&u0.y);
        float2 a1 = __half22float2(*(__half2*)&u1.x), b1 = __half22float2(*(__half2*)&u1.y);
        float2 a2 = __half22float2(*(__half2*)&u2.x), b2 = __half22float2(*(__half2*)&u2.y);
        float4 s;
        s.x = 0.25f * (a0.x + a1.x + a2.x + e3.x);
        s.y = 0.25f * (a0.y + a1.y + a2.y + e3.y);
        s.z = 0.25f * (b0.x + b1.x + b2.x + e3.z);
        s.w = 0.25f * (b0.y + b1.y + b2.y + e3.w);
        *(float4*)(acc + off) = s;
    }
}

// ================= launch =================

extern "C" void kernel_launch(void* const* d_in, const int* in_sizes, int n_in,
                              void* d_out, int out_size, void* d_ws, size_t ws_size,
                              hipStream_t stream) {
    const float* ue = (const float*)d_in[0];
    const float* ie = (const float*)d_in[1];
    const int*   R[3] = { (const int*)d_in[2], (const int*)d_in[5], (const int*)d_in[8] };
    const int*   C[3] = { (const int*)d_in[3], (const int*)d_in[6], (const int*)d_in[9] };
    const float* V[3] = { (const float*)d_in[4], (const float*)d_in[7], (const float*)d_in[10] };
    const int    NZ[3] = { in_sizes[2], in_sizes[5], in_sizes[8] };
    const int    NZT = NZ[0] + NZ[1] + NZ[2];

    float* acc = (float*)d_out;

    // ---- workspace carve (8B aligned) ----
    char* cur = (char*)d_ws;
    int2* pk   = (int2*)cur;  cur += (size_t)NZT * sizeof(int2);
    int* rpg   = (int*)cur;   cur += (((size_t)3 * RPSTRIDE * 4 + 7) & ~7ull);
    int* bcnt  = (int*)cur;   cur += ((NBT * 4 + 7) & ~7ull);
    int* bbase = (int*)cur;   cur += (((NBT + 1) * 4 + 7) & ~7ull);
    int* bfill = (int*)cur;   cur += ((NBT * 4 + 7) & ~7ull);
    __half* x0 = (__half*)cur; cur += (size_t)ELEMS * sizeof(__half);
    __half* x1 = (__half*)cur; cur += (size_t)ELEMS * sizeof(__half);
    __half* x2 = (__half*)cur; cur += (size_t)ELEMS * sizeof(__half);
    __half* tE = (__half*)cur; cur += (size_t)ELEMS * sizeof(__half);
    __half* tT = (__half*)cur; cur += (size_t)ELEMS * sizeof(__half);
    int2* tmp  = (int2*)tE;   // alias: tmp (24MB) lives in tE+tT (38.4MB), dead before SpMMs
    (void)ws_size;

    const int* rpAdj = rpg;
    const int* rpAj  = rpg + RPSTRIDE;
    const int* rpAi  = rpg + 2 * RPSTRIDE;

    int maxNZ = NZ[0]; if (NZ[1] > maxNZ) maxNZ = NZ[1]; if (NZ[2] > maxNZ) maxNZ = NZ[2];

    // ---- build sorted CSR (bucketed counting sort) ----
    hipMemsetAsync(bcnt, 0, NBT * sizeof(int), stream);
    dim3 gH(256, 3);
    bucket_hist<<<gH, 256, 0, stream>>>(R[0], R[1], R[2], NZ[0], NZ[1], NZ[2], bcnt);
    bucket_scan<<<1, 512, 0, stream>>>(bcnt, bbase, bfill);
    dim3 gB((maxNZ + P1_CHUNK - 1) / P1_CHUNK, 3);
    bucket_bin<<<gB, 256, 0, stream>>>(R[0], C[0], V[0], R[1], C[1], V[1], R[2], C[2], V[2],
                                       NZ[0], NZ[1], NZ[2], bfill, tmp);
    bucket_sort<<<NBT, 256, 0, stream>>>(tmp, bbase, pk, rpg);

    const int BLK = 256;
    const int gridI = (ELEMS / 4) / BLK;   // 9375, exact
    const int gridS = NROWS / 4;           // 37500, exact (4 waves = 4 rows per block)

    // ---- x0 = ego (fp16) ----
    lgcn_init4<<<gridI, BLK, 0, stream>>>(ue, ie, x0);

    // ---- hop 1 (coef 0.1) ----
    spmm_plain  <<<gridS, BLK, 0, stream>>>(rpAdj, pk, x0, tE);             // e1
    spmm_plain  <<<gridS, BLK, 0, stream>>>(rpAj,  pk, tE, tT);             // t1
    spmm_combine<<<gridS, BLK, 0, stream>>>(rpAi,  pk, tT, tE, x1, 0.1f);   // x1

    // ---- hop 2 (coef 0.1) ----
    spmm_plain  <<<gridS, BLK, 0, stream>>>(rpAdj, pk, x1, tE);             // e2
    spmm_plain  <<<gridS, BLK, 0, stream>>>(rpAj,  pk, tE, tT);             // t2
    spmm_combine<<<gridS, BLK, 0, stream>>>(rpAi,  pk, tT, tE, x2, 0.1f);   // x2

    // ---- hop 3 (coef 0.0) + fused layer mean ----
    spmm_final  <<<gridS, BLK, 0, stream>>>(rpAdj, pk, x2, x0, x1, acc);
}